// Round 1
// baseline (23212.383 us; speedup 1.0000x reference)
//
#include <hip/hip_runtime.h>
#include <hip/hip_bf16.h>

typedef __attribute__((ext_vector_type(8))) short bf16x8;
typedef __attribute__((ext_vector_type(4))) float f32x4;

#define HD   768
#define NB   64
#define NT   256
#define NGATE 3072   // 4*HD

__device__ __forceinline__ float fast_sig(float x) { return 1.f / (1.f + __expf(-x)); }
__device__ __forceinline__ float fast_tanh(float x) {
  float t = __expf(-2.f * fabsf(x));
  float r = (1.f - t) / (1.f + t);
  return x < 0.f ? -r : r;
}

// ---------------------------------------------------------------------------
// Core per-step GEMM: gates[b][n'] = sum_k A[b][k] * W[n'][k]
//   A is split: k < K0 -> A0 (row stride strideA0), k >= K0 -> A1 (stride 768)
//   W is bf16 row-major [3072][K], rows pre-permuted n' = j*4 + gate
//   Block tile: 64 (all b) x 32 n'.  4 waves, wave w does rows 16w..16w+15.
//   Result left in LDS gl[64][33].
// MFMA 16x16x32 bf16 layouts (gfx950):
//   A: lane l -> row l%16, k = 8*(l/16)+e ;  B: lane l -> col l%16, same k
//   D: lane l, reg r -> row 4*(l/16)+r, col l%16
// ---------------------------------------------------------------------------
__device__ __forceinline__ void mfma_gates(
    const __hip_bfloat16* __restrict__ W, int K,
    const __hip_bfloat16* __restrict__ A0, long strideA0, int K0,
    const __hip_bfloat16* __restrict__ A1,
    int n_base, float (*gl)[33])
{
  int tid = threadIdx.x;
  int w  = tid >> 6;
  int l  = tid & 63;
  int lr = l & 15, lh = l >> 4;
  f32x4 acc0 = {0.f, 0.f, 0.f, 0.f};
  f32x4 acc1 = {0.f, 0.f, 0.f, 0.f};
  int bA = 16 * w + lr;
  const __hip_bfloat16* a0p = A0 + (long)bA * strideA0;
  const __hip_bfloat16* a1p = A1 + bA * HD;
  const __hip_bfloat16* b0p = W + (long)(n_base + lr) * K;
  const __hip_bfloat16* b1p = W + (long)(n_base + 16 + lr) * K;
  int kk = 8 * lh;
  #pragma unroll 4
  for (int k0 = 0; k0 < K; k0 += 32) {
    int ka = k0 + kk;
    bf16x8 av  = (ka < K0) ? *(const bf16x8*)(a0p + ka)
                           : *(const bf16x8*)(a1p + (ka - K0));
    bf16x8 bv0 = *(const bf16x8*)(b0p + ka);
    bf16x8 bv1 = *(const bf16x8*)(b1p + ka);
    acc0 = __builtin_amdgcn_mfma_f32_16x16x32_bf16(av, bv0, acc0, 0, 0, 0);
    acc1 = __builtin_amdgcn_mfma_f32_16x16x32_bf16(av, bv1, acc1, 0, 0, 0);
  }
  #pragma unroll
  for (int r = 0; r < 4; ++r) {
    gl[16 * w + 4 * lh + r][lr]      = acc0[r];
    gl[16 * w + 4 * lh + r][16 + lr] = acc1[r];
  }
}

// ---------------------------------------------------------------------------
// Setup kernels
// ---------------------------------------------------------------------------
__global__ void cvt_bf16_kernel(const float* __restrict__ src,
                                __hip_bfloat16* __restrict__ dst, long n)
{
  long i = (long)blockIdx.x * blockDim.x + threadIdx.x;
  long stride = (long)gridDim.x * blockDim.x;
  for (; i < n; i += stride) dst[i] = __float2bfloat16(src[i]);
}

// dst[n'][k] with n' = j*4 + g (gate-interleaved), K = Kih + 768
// k < Kih -> Wih[g*768+j][k]; else Whh[g*768+j][k-Kih]
__global__ void pack_w_kernel(const float* __restrict__ Wih,
                              const float* __restrict__ Whh,
                              __hip_bfloat16* __restrict__ dst, int Kih)
{
  int K = Kih + HD;
  long total = (long)NGATE * K;
  long stride = (long)gridDim.x * blockDim.x;
  for (long idx = (long)blockIdx.x * blockDim.x + threadIdx.x; idx < total; idx += stride) {
    int np = (int)(idx / K), k = (int)(idx % K);
    int j = np >> 2, g = np & 3;
    int n = g * HD + j;
    float v = (k < Kih) ? Wih[(long)n * Kih + k] : Whh[(long)n * HD + (k - Kih)];
    dst[idx] = __float2bfloat16(v);
  }
}

__global__ void fill_sentinel(float* out, int n, float v)
{
  int i = blockIdx.x * blockDim.x + threadIdx.x;
  if (i < n) out[i] = v;
}

// ---------------------------------------------------------------------------
// Phase 1: BiLSTM step. Grid = 192 blocks: blk<96 fwd, else bwd. nt = blk%96.
// ---------------------------------------------------------------------------
__global__ __launch_bounds__(256) void bilstm_step(
    int step,
    int par,
    const __hip_bfloat16* __restrict__ X16,   // [64][256][768] bf16
    const __hip_bfloat16* __restrict__ WF,    // [3072][1536]
    const __hip_bfloat16* __restrict__ WB,
    const float* __restrict__ bF, const float* __restrict__ bB,
    __hip_bfloat16* __restrict__ H16,         // [2 par][2 dir][64][768]
    float* __restrict__ C32,                  // [2 dir][64][768]
    __hip_bfloat16* __restrict__ L16)         // [64][256][1536]
{
  __shared__ float gl[64][33];
  int blk = blockIdx.x;
  int dir = blk / 96, nt = blk % 96;
  int t = dir ? (255 - step) : step;
  const __hip_bfloat16* W    = dir ? WB : WF;
  const float*          bias = dir ? bB : bF;
  const __hip_bfloat16* A0 = X16 + (long)t * HD;              // + b*(256*768)
  const __hip_bfloat16* H  = H16 + (long)(par * 2 + dir) * (NB * HD);
  __hip_bfloat16* Hn       = H16 + (long)((par ^ 1) * 2 + dir) * (NB * HD);
  float* C = C32 + (long)dir * (NB * HD);

  mfma_gates(W, 1536, A0, (long)NT * HD, 768, H, nt * 32, gl);
  __syncthreads();

  int tid = threadIdx.x;
  #pragma unroll
  for (int u = 0; u < 2; ++u) {
    int e = tid * 2 + u;
    int b = e >> 3, jj = e & 7;
    int j = nt * 8 + jj;
    float vi = gl[b][4 * jj + 0] + bias[j];
    float vf = gl[b][4 * jj + 1] + bias[HD + j];
    float vg = gl[b][4 * jj + 2] + bias[2 * HD + j];
    float vo = gl[b][4 * jj + 3] + bias[3 * HD + j];
    float si = fast_sig(vi), sf = fast_sig(vf), so = fast_sig(vo);
    float tg = fast_tanh(vg);
    int idx = b * HD + j;
    float c = sf * C[idx] + si * tg;
    float h = so * fast_tanh(c);
    C[idx] = c;
    __hip_bfloat16 hb = __float2bfloat16(h);
    Hn[idx] = hb;
    L16[((long)b * NT + t) * 1536 + dir * HD + j] = hb;
  }
}

// ---------------------------------------------------------------------------
// cls x-part: out[b][t][o] = cls_b[o] + sum_k L16[b][t][k]*clsW[o][768+k], t>=1
// block t==0 writes pred0 = (-1, 1).
// ---------------------------------------------------------------------------
__global__ __launch_bounds__(256) void clsx_kernel(
    const __hip_bfloat16* __restrict__ L16,
    const float* __restrict__ clsW, const float* __restrict__ clsb,
    float* __restrict__ out)
{
  int t = blockIdx.x;
  int tid = threadIdx.x;
  if (t == 0) {
    if (tid < 128) {
      int b = tid >> 1, o = tid & 1;
      out[((long)b * NT) * 2 + o] = o ? 1.f : -1.f;
    }
    return;
  }
  if (tid >= 128) return;
  int b = tid >> 1, o = tid & 1;
  const __hip_bfloat16* xp = L16 + ((long)b * NT + t) * 1536;
  const float* w = clsW + o * 2304 + HD;
  float s = clsb[o];
  for (int k = 0; k < 1536; ++k) s += __bfloat162float(xp[k]) * w[k];
  out[((long)b * NT + t) * 2 + o] = s;
}

// ---------------------------------------------------------------------------
// Phase 2a: subword cell. grid 96 blocks.
// A = [ lstm_out[:,s] (1536) | h1s (768) ], W = Wsub' [3072][2304]
// ---------------------------------------------------------------------------
__global__ __launch_bounds__(256) void subw_step(
    int s, int par,
    const __hip_bfloat16* __restrict__ L16,
    const __hip_bfloat16* __restrict__ WS,
    const float* __restrict__ bS,
    __hip_bfloat16* __restrict__ H1S,   // [2][64][768]
    float* __restrict__ C1S,            // [64][768]
    __hip_bfloat16* __restrict__ SUBW,  // [64][1536] = [h1 | c1]
    const int* __restrict__ golds)
{
  __shared__ float gl[64][33];
  int nt = blockIdx.x;
  const __hip_bfloat16* A0 = L16 + (long)s * 1536;
  const __hip_bfloat16* H  = H1S + (long)par * (NB * HD);
  __hip_bfloat16* Hn       = H1S + (long)(par ^ 1) * (NB * HD);

  mfma_gates(WS, 2304, A0, (long)NT * 1536, 1536, H, nt * 32, gl);
  __syncthreads();

  int tid = threadIdx.x;
  __hip_bfloat16 zb = __float2bfloat16(0.f);
  #pragma unroll
  for (int u = 0; u < 2; ++u) {
    int e = tid * 2 + u;
    int b = e >> 3, jj = e & 7;
    int j = nt * 8 + jj;
    float vi = gl[b][4 * jj + 0] + bS[j];
    float vf = gl[b][4 * jj + 1] + bS[HD + j];
    float vg = gl[b][4 * jj + 2] + bS[2 * HD + j];
    float vo = gl[b][4 * jj + 3] + bS[3 * HD + j];
    float si = fast_sig(vi), sf = fast_sig(vf), so = fast_sig(vo);
    float tg = fast_tanh(vg);
    int idx = b * HD + j;
    float c1 = sf * C1S[idx] + si * tg;
    float h1 = so * fast_tanh(c1);
    SUBW[b * 1536 + j]      = __float2bfloat16(h1);
    SUBW[b * 1536 + HD + j] = __float2bfloat16(c1);
    int gg = golds[b * NT + s + 1];
    bool push = (gg == 0);
    Hn[idx]  = push ? __float2bfloat16(h1) : zb;
    C1S[idx] = push ? c1 : 0.f;
  }
}

// ---------------------------------------------------------------------------
// Phase 2b: word cell + cls h2-part (atomics). grid 96 blocks.
// A = [ subword h1,c1 (1536) | h2s (768) ], W = Wword' [3072][2304]
// ---------------------------------------------------------------------------
__global__ __launch_bounds__(256) void word_step(
    int s, int par,
    const __hip_bfloat16* __restrict__ SUBW,
    const __hip_bfloat16* __restrict__ WW,
    const float* __restrict__ bW,
    __hip_bfloat16* __restrict__ H2S,   // [2][64][768]
    float* __restrict__ C2S,            // [64][768]
    const int* __restrict__ golds,
    const float* __restrict__ clsW,
    float* __restrict__ out)
{
  __shared__ float gl[64][33];
  int nt = blockIdx.x;
  const __hip_bfloat16* H = H2S + (long)par * (NB * HD);
  __hip_bfloat16* Hn      = H2S + (long)(par ^ 1) * (NB * HD);

  mfma_gates(WW, 2304, SUBW, 1536, 1536, H, nt * 32, gl);
  __syncthreads();

  int tid = threadIdx.x;
  float p0 = 0.f, p1 = 0.f;
  #pragma unroll
  for (int u = 0; u < 2; ++u) {
    int e = tid * 2 + u;
    int b = e >> 3, jj = e & 7;
    int j = nt * 8 + jj;
    float vi = gl[b][4 * jj + 0] + bW[j];
    float vf = gl[b][4 * jj + 1] + bW[HD + j];
    float vg = gl[b][4 * jj + 2] + bW[2 * HD + j];
    float vo = gl[b][4 * jj + 3] + bW[3 * HD + j];
    float si = fast_sig(vi), sf = fast_sig(vf), so = fast_sig(vo);
    float tg = fast_tanh(vg);
    int idx = b * HD + j;
    float c2 = sf * C2S[idx] + si * tg;
    float h2 = so * fast_tanh(c2);
    int gg = golds[b * NT + s + 1];
    bool push = (gg >= 1);
    Hn[idx] = push ? __float2bfloat16(h2) : H[idx];
    if (push) C2S[idx] = c2;
    p0 += h2 * clsW[j];
    p1 += h2 * clsW[2304 + j];
  }
  // reduce 4 lanes (same b = tid>>2) -> 1 atomic pair
  p0 += __shfl_down(p0, 1); p1 += __shfl_down(p1, 1);
  p0 += __shfl_down(p0, 2); p1 += __shfl_down(p1, 2);
  if ((tid & 3) == 0) {
    int b = tid >> 2;
    atomicAdd(&out[((long)b * NT + s + 1) * 2 + 0], p0);
    atomicAdd(&out[((long)b * NT + s + 1) * 2 + 1], p1);
  }
}

// ---------------------------------------------------------------------------
// Host launcher
// ---------------------------------------------------------------------------
extern "C" void kernel_launch(void* const* d_in, const int* in_sizes, int n_in,
                              void* d_out, int out_size, void* d_ws, size_t ws_size,
                              hipStream_t stream)
{
  const float* x     = (const float*)d_in[0];
  const int*   golds = (const int*)d_in[1];
  const float* WihF  = (const float*)d_in[2];
  const float* WhhF  = (const float*)d_in[3];
  const float* bF    = (const float*)d_in[4];
  const float* WihB  = (const float*)d_in[5];
  const float* WhhB  = (const float*)d_in[6];
  const float* bB    = (const float*)d_in[7];
  const float* WihS  = (const float*)d_in[8];
  const float* WhhS  = (const float*)d_in[9];
  const float* bS    = (const float*)d_in[10];
  const float* WihW  = (const float*)d_in[11];
  const float* WhhW  = (const float*)d_in[12];
  const float* bW    = (const float*)d_in[13];
  const float* clsW  = (const float*)d_in[14];
  const float* clsb  = (const float*)d_in[15];
  float* out = (float*)d_out;

  // workspace layout (bytes)
  const size_t OFF_X16  = 0;                     // 64*256*768 bf16   = 25165824
  const size_t OFF_WF   = 25165824;              // 3072*1536 bf16    =  9437184
  const size_t OFF_WB   = 34603008;
  const size_t OFF_WS   = 44040192;              // 3072*2304 bf16    = 14155776
  const size_t OFF_WW   = 58195968;
  const size_t OFF_L16  = 72351744;              // 64*256*1536 bf16  = 50331648
  const size_t OFF_H16  = 122683392;             // 2*2*64*768 bf16   =   393216
  const size_t OFF_H1S  = 123076608;             // 2*64*768 bf16     =   196608
  const size_t OFF_H2S  = 123273216;
  const size_t OFF_C32  = 123469824;             // 2*64*768 f32      =   393216
  const size_t OFF_C1S  = 123863040;             // 64*768 f32        =   196608
  const size_t OFF_C2S  = 124059648;
  const size_t OFF_SUBW = 124256256;             // 64*1536 bf16      =   196608
  const size_t WS_NEEDED = 124452864;

  if (ws_size < WS_NEEDED) {
    // diagnosable failure: sentinel so absmax ~12345 signals "workspace too small"
    fill_sentinel<<<(out_size + 255) / 256, 256, 0, stream>>>(out, out_size, 12345.f);
    return;
  }

  char* ws = (char*)d_ws;
  __hip_bfloat16* X16  = (__hip_bfloat16*)(ws + OFF_X16);
  __hip_bfloat16* WF   = (__hip_bfloat16*)(ws + OFF_WF);
  __hip_bfloat16* WB   = (__hip_bfloat16*)(ws + OFF_WB);
  __hip_bfloat16* WS   = (__hip_bfloat16*)(ws + OFF_WS);
  __hip_bfloat16* WW   = (__hip_bfloat16*)(ws + OFF_WW);
  __hip_bfloat16* L16  = (__hip_bfloat16*)(ws + OFF_L16);
  __hip_bfloat16* H16  = (__hip_bfloat16*)(ws + OFF_H16);
  __hip_bfloat16* H1S  = (__hip_bfloat16*)(ws + OFF_H1S);
  __hip_bfloat16* H2S  = (__hip_bfloat16*)(ws + OFF_H2S);
  float*          C32  = (float*)(ws + OFF_C32);
  float*          C1S  = (float*)(ws + OFF_C1S);
  float*          C2S  = (float*)(ws + OFF_C2S);
  __hip_bfloat16* SUBW = (__hip_bfloat16*)(ws + OFF_SUBW);

  // setup: pack weights (gate-interleaved bf16), convert x, zero states
  pack_w_kernel<<<2048, 256, 0, stream>>>(WihF, WhhF, WF, 768);
  pack_w_kernel<<<2048, 256, 0, stream>>>(WihB, WhhB, WB, 768);
  pack_w_kernel<<<2048, 256, 0, stream>>>(WihS, WhhS, WS, 1536);
  pack_w_kernel<<<2048, 256, 0, stream>>>(WihW, WhhW, WW, 1536);
  cvt_bf16_kernel<<<2048, 256, 0, stream>>>(x, X16, (long)NB * NT * HD);
  hipMemsetAsync(ws + OFF_H16, 0, OFF_SUBW - OFF_H16, stream);

  // phase 1: BiLSTM (fwd + bwd in lockstep)
  for (int s = 0; s < NT; ++s)
    bilstm_step<<<192, 256, 0, stream>>>(s, s & 1, X16, WF, WB, bF, bB, H16, C32, L16);

  // cls x-part + pred0
  clsx_kernel<<<NT, 256, 0, stream>>>(L16, clsW, clsb, out);

  // phase 2: stack-LSTM scan (stacks reduced to gated state carry)
  for (int s = 0; s < NT - 1; ++s) {
    subw_step<<<96, 256, 0, stream>>>(s, s & 1, L16, WS, bS, H1S, C1S, SUBW, golds);
    word_step<<<96, 256, 0, stream>>>(s, s & 1, SUBW, WW, bW, H2S, C2S, golds, clsW, out);
  }
}

// Round 2
// 23207.634 us; speedup vs baseline: 1.0002x; 1.0002x over previous
//
#include <hip/hip_runtime.h>
#include <hip/hip_bf16.h>

typedef __attribute__((ext_vector_type(8))) short bf16x8;
typedef __attribute__((ext_vector_type(4))) float f32x4;

#define HD   768
#define NB   64
#define NT   256
#define NGATE 3072   // 4*HD

__device__ __forceinline__ float fast_sig(float x) { return 1.f / (1.f + __expf(-x)); }
__device__ __forceinline__ float fast_tanh(float x) {
  float t = __expf(-2.f * fabsf(x));
  float r = (1.f - t) / (1.f + t);
  return x < 0.f ? -r : r;
}

// ---------------------------------------------------------------------------
// Core per-step GEMM: gates[b][n'] = sum_k A[b][k] * W[n'][k]
//   A is split: k < K0 -> A0 (row stride strideA0), k >= K0 -> A1 (stride 768)
//   W is bf16 row-major [3072][K], rows pre-permuted n' = j*4 + gate
//   Block tile: 64 (all b) x 32 n'.  4 waves, wave w does rows 16w..16w+15.
//   Result left in LDS gl[64][33].
// MFMA 16x16x32 bf16 layouts (gfx950):
//   A: lane l -> row l%16, k = 8*(l/16)+e ;  B: lane l -> col l%16, same k
//   D: lane l, reg r -> row 4*(l/16)+r, col l%16
// ---------------------------------------------------------------------------
__device__ __forceinline__ void mfma_gates(
    const __hip_bfloat16* __restrict__ W, int K,
    const __hip_bfloat16* __restrict__ A0, long strideA0, int K0,
    const __hip_bfloat16* __restrict__ A1,
    int n_base, float (*gl)[33])
{
  int tid = threadIdx.x;
  int w  = tid >> 6;
  int l  = tid & 63;
  int lr = l & 15, lh = l >> 4;
  f32x4 acc0 = {0.f, 0.f, 0.f, 0.f};
  f32x4 acc1 = {0.f, 0.f, 0.f, 0.f};
  int bA = 16 * w + lr;
  const __hip_bfloat16* a0p = A0 + (long)bA * strideA0;
  const __hip_bfloat16* a1p = A1 + bA * HD;
  const __hip_bfloat16* b0p = W + (long)(n_base + lr) * K;
  const __hip_bfloat16* b1p = W + (long)(n_base + 16 + lr) * K;
  int kk = 8 * lh;
  #pragma unroll 4
  for (int k0 = 0; k0 < K; k0 += 32) {
    int ka = k0 + kk;
    bf16x8 av  = (ka < K0) ? *(const bf16x8*)(a0p + ka)
                           : *(const bf16x8*)(a1p + (ka - K0));
    bf16x8 bv0 = *(const bf16x8*)(b0p + ka);
    bf16x8 bv1 = *(const bf16x8*)(b1p + ka);
    acc0 = __builtin_amdgcn_mfma_f32_16x16x32_bf16(av, bv0, acc0, 0, 0, 0);
    acc1 = __builtin_amdgcn_mfma_f32_16x16x32_bf16(av, bv1, acc1, 0, 0, 0);
  }
  #pragma unroll
  for (int r = 0; r < 4; ++r) {
    gl[16 * w + 4 * lh + r][lr]      = acc0[r];
    gl[16 * w + 4 * lh + r][16 + lr] = acc1[r];
  }
}

// ---------------------------------------------------------------------------
// Setup kernels
// ---------------------------------------------------------------------------
__global__ void cvt_bf16_kernel(const float* __restrict__ src,
                                __hip_bfloat16* __restrict__ dst, long n)
{
  long i = (long)blockIdx.x * blockDim.x + threadIdx.x;
  long stride = (long)gridDim.x * blockDim.x;
  for (; i < n; i += stride) dst[i] = __float2bfloat16(src[i]);
}

// dst[n'][k] with n' = j*4 + g (gate-interleaved), K = Kih + 768
// k < Kih -> Wih[g*768+j][k]; else Whh[g*768+j][k-Kih]
__global__ void pack_w_kernel(const float* __restrict__ Wih,
                              const float* __restrict__ Whh,
                              __hip_bfloat16* __restrict__ dst, int Kih)
{
  int K = Kih + HD;
  long total = (long)NGATE * K;
  long stride = (long)gridDim.x * blockDim.x;
  for (long idx = (long)blockIdx.x * blockDim.x + threadIdx.x; idx < total; idx += stride) {
    int np = (int)(idx / K), k = (int)(idx % K);
    int j = np >> 2, g = np & 3;
    int n = g * HD + j;
    float v = (k < Kih) ? Wih[(long)n * Kih + k] : Whh[(long)n * HD + (k - Kih)];
    dst[idx] = __float2bfloat16(v);
  }
}

__global__ void fill_sentinel(float* out, int n, float v)
{
  int i = blockIdx.x * blockDim.x + threadIdx.x;
  if (i < n) out[i] = v;
}

// ---------------------------------------------------------------------------
// Phase 1: BiLSTM step. Grid = 192 blocks: blk<96 fwd, else bwd. nt = blk%96.
// ---------------------------------------------------------------------------
__global__ __launch_bounds__(256) void bilstm_step(
    int step,
    int par,
    const __hip_bfloat16* __restrict__ X16,   // [64][256][768] bf16
    const __hip_bfloat16* __restrict__ WF,    // [3072][1536]
    const __hip_bfloat16* __restrict__ WB,
    const float* __restrict__ bF, const float* __restrict__ bB,
    __hip_bfloat16* __restrict__ H16,         // [2 par][2 dir][64][768]
    float* __restrict__ C32,                  // [2 dir][64][768]
    __hip_bfloat16* __restrict__ L16)         // [64][256][1536]
{
  __shared__ float gl[64][33];
  int blk = blockIdx.x;
  int dir = blk / 96, nt = blk % 96;
  int t = dir ? (255 - step) : step;
  const __hip_bfloat16* W    = dir ? WB : WF;
  const float*          bias = dir ? bB : bF;
  const __hip_bfloat16* A0 = X16 + (long)t * HD;              // + b*(256*768)
  const __hip_bfloat16* H  = H16 + (long)(par * 2 + dir) * (NB * HD);
  __hip_bfloat16* Hn       = H16 + (long)((par ^ 1) * 2 + dir) * (NB * HD);
  float* C = C32 + (long)dir * (NB * HD);

  mfma_gates(W, 1536, A0, (long)NT * HD, 768, H, nt * 32, gl);
  __syncthreads();

  int tid = threadIdx.x;
  #pragma unroll
  for (int u = 0; u < 2; ++u) {
    int e = tid * 2 + u;
    int b = e >> 3, jj = e & 7;
    int j = nt * 8 + jj;
    float vi = gl[b][4 * jj + 0] + bias[j];
    float vf = gl[b][4 * jj + 1] + bias[HD + j];
    float vg = gl[b][4 * jj + 2] + bias[2 * HD + j];
    float vo = gl[b][4 * jj + 3] + bias[3 * HD + j];
    float si = fast_sig(vi), sf = fast_sig(vf), so = fast_sig(vo);
    float tg = fast_tanh(vg);
    int idx = b * HD + j;
    float c = sf * C[idx] + si * tg;
    float h = so * fast_tanh(c);
    C[idx] = c;
    __hip_bfloat16 hb = __float2bfloat16(h);
    Hn[idx] = hb;
    L16[((long)b * NT + t) * 1536 + dir * HD + j] = hb;
  }
}

// ---------------------------------------------------------------------------
// cls x-part: out[b][t][o] = cls_b[o] + sum_k L16[b][t][k]*clsW[o][768+k], t>=1
// block t==0 writes pred0 = (-1, 1).
// ---------------------------------------------------------------------------
__global__ __launch_bounds__(256) void clsx_kernel(
    const __hip_bfloat16* __restrict__ L16,
    const float* __restrict__ clsW, const float* __restrict__ clsb,
    float* __restrict__ out)
{
  int t = blockIdx.x;
  int tid = threadIdx.x;
  if (t == 0) {
    if (tid < 128) {
      int b = tid >> 1, o = tid & 1;
      out[((long)b * NT) * 2 + o] = o ? 1.f : -1.f;
    }
    return;
  }
  if (tid >= 128) return;
  int b = tid >> 1, o = tid & 1;
  const __hip_bfloat16* xp = L16 + ((long)b * NT + t) * 1536;
  const float* w = clsW + o * 2304 + HD;
  float s = clsb[o];
  for (int k = 0; k < 1536; ++k) s += __bfloat162float(xp[k]) * w[k];
  out[((long)b * NT + t) * 2 + o] = s;
}

// ---------------------------------------------------------------------------
// Phase 2a: subword cell. grid 96 blocks.
// A = [ lstm_out[:,s] (1536) | h1s (768) ], W = Wsub' [3072][2304]
// ---------------------------------------------------------------------------
__global__ __launch_bounds__(256) void subw_step(
    int s, int par,
    const __hip_bfloat16* __restrict__ L16,
    const __hip_bfloat16* __restrict__ WS,
    const float* __restrict__ bS,
    __hip_bfloat16* __restrict__ H1S,   // [2][64][768]
    float* __restrict__ C1S,            // [64][768]
    __hip_bfloat16* __restrict__ SUBW,  // [64][1536] = [h1 | c1]
    const int* __restrict__ golds)
{
  __shared__ float gl[64][33];
  int nt = blockIdx.x;
  const __hip_bfloat16* A0 = L16 + (long)s * 1536;
  const __hip_bfloat16* H  = H1S + (long)par * (NB * HD);
  __hip_bfloat16* Hn       = H1S + (long)(par ^ 1) * (NB * HD);

  mfma_gates(WS, 2304, A0, (long)NT * 1536, 1536, H, nt * 32, gl);
  __syncthreads();

  int tid = threadIdx.x;
  __hip_bfloat16 zb = __float2bfloat16(0.f);
  #pragma unroll
  for (int u = 0; u < 2; ++u) {
    int e = tid * 2 + u;
    int b = e >> 3, jj = e & 7;
    int j = nt * 8 + jj;
    float vi = gl[b][4 * jj + 0] + bS[j];
    float vf = gl[b][4 * jj + 1] + bS[HD + j];
    float vg = gl[b][4 * jj + 2] + bS[2 * HD + j];
    float vo = gl[b][4 * jj + 3] + bS[3 * HD + j];
    float si = fast_sig(vi), sf = fast_sig(vf), so = fast_sig(vo);
    float tg = fast_tanh(vg);
    int idx = b * HD + j;
    float c1 = sf * C1S[idx] + si * tg;
    float h1 = so * fast_tanh(c1);
    SUBW[b * 1536 + j]      = __float2bfloat16(h1);
    SUBW[b * 1536 + HD + j] = __float2bfloat16(c1);
    int gg = golds[b * NT + s + 1];
    bool push = (gg == 0);
    Hn[idx]  = push ? __float2bfloat16(h1) : zb;
    C1S[idx] = push ? c1 : 0.f;
  }
}

// ---------------------------------------------------------------------------
// Phase 2b: word cell + cls h2-part (atomics). grid 96 blocks.
// A = [ subword h1,c1 (1536) | h2s (768) ], W = Wword' [3072][2304]
// ---------------------------------------------------------------------------
__global__ __launch_bounds__(256) void word_step(
    int s, int par,
    const __hip_bfloat16* __restrict__ SUBW,
    const __hip_bfloat16* __restrict__ WW,
    const float* __restrict__ bW,
    __hip_bfloat16* __restrict__ H2S,   // [2][64][768]
    float* __restrict__ C2S,            // [64][768]
    const int* __restrict__ golds,
    const float* __restrict__ clsW,
    float* __restrict__ out)
{
  __shared__ float gl[64][33];
  int nt = blockIdx.x;
  const __hip_bfloat16* H = H2S + (long)par * (NB * HD);
  __hip_bfloat16* Hn      = H2S + (long)(par ^ 1) * (NB * HD);

  mfma_gates(WW, 2304, SUBW, 1536, 1536, H, nt * 32, gl);
  __syncthreads();

  int tid = threadIdx.x;
  float p0 = 0.f, p1 = 0.f;
  #pragma unroll
  for (int u = 0; u < 2; ++u) {
    int e = tid * 2 + u;
    int b = e >> 3, jj = e & 7;
    int j = nt * 8 + jj;
    float vi = gl[b][4 * jj + 0] + bW[j];
    float vf = gl[b][4 * jj + 1] + bW[HD + j];
    float vg = gl[b][4 * jj + 2] + bW[2 * HD + j];
    float vo = gl[b][4 * jj + 3] + bW[3 * HD + j];
    float si = fast_sig(vi), sf = fast_sig(vf), so = fast_sig(vo);
    float tg = fast_tanh(vg);
    int idx = b * HD + j;
    float c2 = sf * C2S[idx] + si * tg;
    float h2 = so * fast_tanh(c2);
    int gg = golds[b * NT + s + 1];
    bool push = (gg >= 1);
    Hn[idx] = push ? __float2bfloat16(h2) : H[idx];
    if (push) C2S[idx] = c2;
    p0 += h2 * clsW[j];
    p1 += h2 * clsW[2304 + j];
  }
  // reduce 4 lanes (same b = tid>>2) -> 1 atomic pair
  p0 += __shfl_down(p0, 1); p1 += __shfl_down(p1, 1);
  p0 += __shfl_down(p0, 2); p1 += __shfl_down(p1, 2);
  if ((tid & 3) == 0) {
    int b = tid >> 2;
    atomicAdd(&out[((long)b * NT + s + 1) * 2 + 0], p0);
    atomicAdd(&out[((long)b * NT + s + 1) * 2 + 1], p1);
  }
}

// ---------------------------------------------------------------------------
// Host launcher
// ---------------------------------------------------------------------------
extern "C" void kernel_launch(void* const* d_in, const int* in_sizes, int n_in,
                              void* d_out, int out_size, void* d_ws, size_t ws_size,
                              hipStream_t stream)
{
  const float* x     = (const float*)d_in[0];
  const int*   golds = (const int*)d_in[1];
  const float* WihF  = (const float*)d_in[2];
  const float* WhhF  = (const float*)d_in[3];
  const float* bF    = (const float*)d_in[4];
  const float* WihB  = (const float*)d_in[5];
  const float* WhhB  = (const float*)d_in[6];
  const float* bB    = (const float*)d_in[7];
  const float* WihS  = (const float*)d_in[8];
  const float* WhhS  = (const float*)d_in[9];
  const float* bS    = (const float*)d_in[10];
  const float* WihW  = (const float*)d_in[11];
  const float* WhhW  = (const float*)d_in[12];
  const float* bW    = (const float*)d_in[13];
  const float* clsW  = (const float*)d_in[14];
  const float* clsb  = (const float*)d_in[15];
  float* out = (float*)d_out;

  // workspace layout (bytes)
  const size_t OFF_X16  = 0;                     // 64*256*768 bf16   = 25165824
  const size_t OFF_WF   = 25165824;              // 3072*1536 bf16    =  9437184
  const size_t OFF_WB   = 34603008;
  const size_t OFF_WS   = 44040192;              // 3072*2304 bf16    = 14155776
  const size_t OFF_WW   = 58195968;
  const size_t OFF_L16  = 72351744;              // 64*256*1536 bf16  = 50331648
  const size_t OFF_H16  = 122683392;             // 2*2*64*768 bf16   =   393216
  const size_t OFF_H1S  = 123076608;             // 2*64*768 bf16     =   196608
  const size_t OFF_H2S  = 123273216;
  const size_t OFF_C32  = 123469824;             // 2*64*768 f32      =   393216
  const size_t OFF_C1S  = 123863040;             // 64*768 f32        =   196608
  const size_t OFF_C2S  = 124059648;
  const size_t OFF_SUBW = 124256256;             // 64*1536 bf16      =   196608
  const size_t WS_NEEDED = 124452864;

  if (ws_size < WS_NEEDED) {
    // diagnosable failure: sentinel so absmax ~12345 signals "workspace too small"
    fill_sentinel<<<(out_size + 255) / 256, 256, 0, stream>>>(out, out_size, 12345.f);
    return;
  }

  char* ws = (char*)d_ws;
  __hip_bfloat16* X16  = (__hip_bfloat16*)(ws + OFF_X16);
  __hip_bfloat16* WF   = (__hip_bfloat16*)(ws + OFF_WF);
  __hip_bfloat16* WB   = (__hip_bfloat16*)(ws + OFF_WB);
  __hip_bfloat16* WS   = (__hip_bfloat16*)(ws + OFF_WS);
  __hip_bfloat16* WW   = (__hip_bfloat16*)(ws + OFF_WW);
  __hip_bfloat16* L16  = (__hip_bfloat16*)(ws + OFF_L16);
  __hip_bfloat16* H16  = (__hip_bfloat16*)(ws + OFF_H16);
  __hip_bfloat16* H1S  = (__hip_bfloat16*)(ws + OFF_H1S);
  __hip_bfloat16* H2S  = (__hip_bfloat16*)(ws + OFF_H2S);
  float*          C32  = (float*)(ws + OFF_C32);
  float*          C1S  = (float*)(ws + OFF_C1S);
  float*          C2S  = (float*)(ws + OFF_C2S);
  __hip_bfloat16* SUBW = (__hip_bfloat16*)(ws + OFF_SUBW);

  // setup: pack weights (gate-interleaved bf16), convert x, zero states
  pack_w_kernel<<<2048, 256, 0, stream>>>(WihF, WhhF, WF, 768);
  pack_w_kernel<<<2048, 256, 0, stream>>>(WihB, WhhB, WB, 768);
  pack_w_kernel<<<2048, 256, 0, stream>>>(WihS, WhhS, WS, 1536);
  pack_w_kernel<<<2048, 256, 0, stream>>>(WihW, WhhW, WW, 1536);
  cvt_bf16_kernel<<<2048, 256, 0, stream>>>(x, X16, (long)NB * NT * HD);
  hipMemsetAsync(ws + OFF_H16, 0, OFF_SUBW - OFF_H16, stream);

  // phase 1: BiLSTM (fwd + bwd in lockstep)
  for (int s = 0; s < NT; ++s)
    bilstm_step<<<192, 256, 0, stream>>>(s, s & 1, X16, WF, WB, bF, bB, H16, C32, L16);

  // cls x-part + pred0
  clsx_kernel<<<NT, 256, 0, stream>>>(L16, clsW, clsb, out);

  // phase 2: stack-LSTM scan (stacks reduced to gated state carry)
  for (int s = 0; s < NT - 1; ++s) {
    subw_step<<<96, 256, 0, stream>>>(s, s & 1, L16, WS, bS, H1S, C1S, SUBW, golds);
    word_step<<<96, 256, 0, stream>>>(s, s & 1, SUBW, WW, bW, H2S, C2S, golds, clsW, out);
  }
}